// Round 4
// baseline (178.446 us; speedup 1.0000x reference)
//
#include <hip/hip_runtime.h>
#include <math.h>

#define B_  4
#define L_  32768
#define DI  20
#define NS  10
#define TBLK 128        // timesteps per chunk/block
#define NCB  (L_/TBLK)  // 256 chunks per (b,d)
#define K_   8          // timesteps per lane in scan (16 lanes * 8 = 128)

// workspace float offsets (total 8,294,480 floats = 33.2 MB)
#define OFF_D   0u
#define OFF_U   2621440u
#define OFF_B   5242880u
#define OFF_C   6553600u
#define OFF_AP  7864320u   // per-chunk A-products  [bd][n][NCB]
#define OFF_RS  8069120u   // K1: r_end; kC2 overwrites with r_in (in place)
#define OFF_SC  8273920u   // K1: delta sums; kC2 overwrites with cum (in place)
#define OFF_TOT 8294400u   // 80

__device__ __forceinline__ void ld8(float* r, const float* p) {
    *(float4*)(r)     = *(const float4*)(p);
    *(float4*)(r + 4) = *(const float4*)(p + 4);
}

// ---------------- K1: fused pointwise preprocessing + chunk-local scan ----------
// 320 threads. Phase P1/P2 (tid<256, 2 threads/timestep): in-proj, conv3, silu,
// x-proj, softmax(dt); store delta/u/B/C to global AND stage delta, delta*u, B
// into LDS. Phase P3 (all 320 = 20 d x 16 lanes): chunk-local 16-lane scan ->
// per-chunk summaries (A-product, r_end, delta-sum).
__global__ __launch_bounds__(320) void k1(
    const float* __restrict__ x, const float* __restrict__ w_in,
    const float* __restrict__ b_in, const float* __restrict__ conv_k,
    const float* __restrict__ conv_b, const float* __restrict__ w_x,
    const float* __restrict__ b_x, const float* __restrict__ w_dt,
    const float* __restrict__ b_dt, const float* __restrict__ A_log,
    float* __restrict__ dws, float* __restrict__ uws,
    float* __restrict__ Bws, float* __restrict__ Cws,
    float* __restrict__ ap_ws, float* __restrict__ rs_ws, float* __restrict__ sc_ws)
{
    // pool: first 2736 floats = xs[130][21] then reused as dS[20][132]
    //       next  2736 floats = h2[130][21] then reused as duS[20][132]
    // (2736 keeps the second region 16B-aligned for float4 LDS reads)
    __shared__ float pool[5472];
    __shared__ float BS[1320];     // B staging [10][132]
    __shared__ float win_s[400];   // (i,o) first 20 cols of (20,40)
    __shared__ float ck_s[1200];   // (w,i,o)
    __shared__ float wx_s[500];    // (o,j)
    __shared__ float wdt_s[100];   // (r,d)
    __shared__ float bin_s[20], cb_s[20], bx_s[25], bdt_s[20];

    const int tid = threadIdx.x;
    const int b   = blockIdx.y;
    const int blk = blockIdx.x;
    const int l0  = blk * TBLK;

    for (int i = tid; i < 400;  i += 320) win_s[i] = w_in[(i/20)*40 + (i%20)];
    for (int i = tid; i < 1200; i += 320) ck_s[i]  = conv_k[i];
    for (int i = tid; i < 500;  i += 320) wx_s[i]  = w_x[i];
    for (int i = tid; i < 100;  i += 320) wdt_s[i] = w_dt[i];
    if (tid < 20) { bin_s[tid] = b_in[tid]; cb_s[tid] = conv_b[tid]; bdt_s[tid] = b_dt[tid]; }
    if (tid < 25) bx_s[tid] = b_x[tid];

    // x rows for l in [l0-2, l0+128) -> xs
    for (int idx = tid; idx < 130*20; idx += 320) {
        int p = idx / 20, i = idx - p*20;
        int l = l0 - 2 + p;
        pool[p*21 + i] = (l >= 0) ? x[((size_t)b*L_ + l)*DI + i] : 0.0f;
    }
    __syncthreads();

    // P1: h2 = xs @ w_in + b_in ; 260 tasks = 130 rows x 2 halves
    for (int tau = tid; tau < 260; tau += 320) {
        int p = tau >> 1, hf2 = tau & 1, ob2 = hf2*10;
        int l = l0 - 2 + p;
        float acc[10];
        if (l < 0) {
            #pragma unroll
            for (int o = 0; o < 10; o++) acc[o] = 0.0f;
        } else {
            #pragma unroll
            for (int o = 0; o < 10; o++) acc[o] = bin_s[ob2 + o];
            #pragma unroll
            for (int i = 0; i < 20; i++) {
                float xv = pool[p*21 + i];
                #pragma unroll
                for (int o = 0; o < 10; o++) acc[o] = fmaf(xv, win_s[i*20 + ob2 + o], acc[o]);
            }
        }
        #pragma unroll
        for (int o = 0; o < 10; o++) pool[2736 + p*21 + ob2 + o] = acc[o];
    }
    __syncthreads();

    float u10[10], dl[10], xp[25];
    int tl = 0, hf = 0, ob = 0;
    if (tid < 256) {
        tl = tid >> 1; hf = tid & 1; ob = hf*10;
        // conv3 causal + silu (own 10 channels)
        #pragma unroll
        for (int o = 0; o < 10; o++) u10[o] = cb_s[ob + o];
        #pragma unroll
        for (int w = 0; w < 3; w++) {
            #pragma unroll
            for (int i = 0; i < 20; i++) {
                float hv = pool[2736 + (tl + w)*21 + i];
                const float* ck = &ck_s[(w*20 + i)*20 + ob];
                #pragma unroll
                for (int o = 0; o < 10; o++) u10[o] = fmaf(hv, ck[o], u10[o]);
            }
        }
        #pragma unroll
        for (int o = 0; o < 10; o++) u10[o] = u10[o] / (1.0f + __expf(-u10[o]));

        // xp = u @ w_x + b_x (partial over own half, pair-reduce)
        #pragma unroll
        for (int j = 0; j < 25; j++) xp[j] = hf ? 0.0f : bx_s[j];
        #pragma unroll
        for (int o = 0; o < 10; o++) {
            float uv = u10[o];
            #pragma unroll
            for (int j = 0; j < 25; j++) xp[j] = fmaf(uv, wx_s[(ob + o)*25 + j], xp[j]);
        }
        #pragma unroll
        for (int j = 0; j < 25; j++) xp[j] += __shfl_xor(xp[j], 1);

        // delta = softmax(xp[:5] @ w_dt + b_dt), own 10 d's, pair-reduce max/sum
        #pragma unroll
        for (int d = 0; d < 10; d++) dl[d] = bdt_s[ob + d];
        #pragma unroll
        for (int r = 0; r < 5; r++) {
            float dv = xp[r];
            #pragma unroll
            for (int d = 0; d < 10; d++) dl[d] = fmaf(dv, wdt_s[r*20 + ob + d], dl[d]);
        }
        float m = dl[0];
        #pragma unroll
        for (int d = 1; d < 10; d++) m = fmaxf(m, dl[d]);
        m = fmaxf(m, __shfl_xor(m, 1));
        float sum = 0.0f;
        #pragma unroll
        for (int d = 0; d < 10; d++) { dl[d] = __expf(dl[d] - m); sum += dl[d]; }
        sum += __shfl_xor(sum, 1);
        float inv = 1.0f / sum;
        #pragma unroll
        for (int d = 0; d < 10; d++) dl[d] *= inv;
    }
    __syncthreads();   // all h2/xs reads complete -> safe to overwrite pool

    if (tid < 256) {
        const int l = l0 + tl;
        #pragma unroll
        for (int d = 0; d < 10; d++) {
            size_t o = (size_t)(b*DI + ob + d)*L_ + l;
            dws[o] = dl[d];
            uws[o] = u10[d];
            pool[(ob + d)*132 + tl]        = dl[d];           // dS
            pool[2736 + (ob + d)*132 + tl] = dl[d]*u10[d];    // duS
        }
        if (hf == 0) {
            #pragma unroll
            for (int n = 0; n < NS; n++) {
                Bws[(size_t)(b*NS + n)*L_ + l] = xp[5 + n];
                BS[n*132 + tl] = xp[5 + n];
            }
        } else {
            #pragma unroll
            for (int n = 0; n < NS; n++) Cws[(size_t)(b*NS + n)*L_ + l] = xp[15 + n];
        }
    }
    __syncthreads();

    // P3: chunk-local scan, 20 d x 16 lanes
    const int d  = tid >> 4;
    const int s  = tid & 15;
    const int bd = b*DI + d;

    float d8[8], du8[8];
    ld8(d8,  &pool[d*132 + 8*s]);
    ld8(du8, &pool[2736 + d*132 + 8*s]);

    float ssum = 0.0f;
    #pragma unroll
    for (int j = 0; j < 8; j++) ssum += d8[j];
    #pragma unroll
    for (int off = 1; off < 16; off <<= 1) ssum += __shfl_xor(ssum, off, 16);
    if (s == 0) sc_ws[(size_t)bd*NCB + blk] = ssum;

    #pragma unroll 1
    for (int n = 0; n < NS; n++) {
        const float A = -__expf(A_log[d*NS + n]);
        float B8[8];
        ld8(B8, &BS[n*132 + 8*s]);
        float Ac = 1.0f, Bc = 0.0f;
        #pragma unroll
        for (int j = 0; j < 8; j++) {
            float a = __expf(A*d8[j]);
            Bc = fmaf(a, Bc, du8[j]*B8[j]);
            Ac *= a;
        }
        #pragma unroll
        for (int off = 1; off < 16; off <<= 1) {
            float aP = __shfl_up(Ac, off, 16);
            float bP = __shfl_up(Bc, off, 16);
            if (s >= off) { Bc = fmaf(Ac, bP, Bc); Ac *= aP; }
        }
        if (s == 15) {
            size_t o = ((size_t)bd*NS + n)*NCB + blk;
            ap_ws[o] = Ac;
            rs_ws[o] = Bc;
        }
    }
}

// ---------------- kC2: inter-chunk scan (one wave per (b,d)) ----------------
__global__ __launch_bounds__(64) void kC2(
    const float* __restrict__ ap_ws, float* __restrict__ rs_ws,
    float* __restrict__ sc_ws, float* __restrict__ tot_ws)
{
    const int bd   = blockIdx.x;
    const int lane = threadIdx.x;
    const size_t sb = (size_t)bd*NCB + lane*4;

    float4 sv = *(const float4*)(sc_ws + sb);
    float l1 = sv.x, l2 = l1 + sv.y, l3 = l2 + sv.z, l4 = l3 + sv.w;
    float inc = l4;
    #pragma unroll
    for (int off = 1; off < 64; off <<= 1) {
        float t = __shfl_up(inc, off);
        if (lane >= off) inc += t;
    }
    float ex = __shfl_up(inc, 1);
    if (lane == 0) ex = 0.0f;
    *(float4*)(sc_ws + sb) = make_float4(ex, ex + l1, ex + l2, ex + l3);
    if (lane == 63) tot_ws[bd] = inc;

    #pragma unroll 1
    for (int n = 0; n < NS; n++) {
        const size_t base = ((size_t)bd*NS + n)*NCB + lane*4;
        float4 av = *(const float4*)(ap_ws + base);
        float4 rv = *(const float4*)(rs_ws + base);
        float Ac = av.x, Bc = rv.x;
        Bc = fmaf(av.y, Bc, rv.y); Ac *= av.y;
        Bc = fmaf(av.z, Bc, rv.z); Ac *= av.z;
        Bc = fmaf(av.w, Bc, rv.w); Ac *= av.w;
        #pragma unroll
        for (int off = 1; off < 64; off <<= 1) {
            float aP = __shfl_up(Ac, off);
            float bP = __shfl_up(Bc, off);
            if (lane >= off) { Bc = fmaf(Ac, bP, Bc); Ac *= aP; }
        }
        float pB = __shfl_up(Bc, 1);
        if (lane == 0) pB = 0.0f;
        float r  = pB;                 // initial state is 0
        float o0 = r; r = fmaf(av.x, r, rv.x);
        float o1 = r; r = fmaf(av.y, r, rv.y);
        float o2 = r; r = fmaf(av.z, r, rv.z);
        float o3 = r;
        *(float4*)(rs_ws + base) = make_float4(o0, o1, o2, o3);
    }
}

// ---------------- kD2: final scans + damp + y (LDS transpose out) ------------
__global__ __launch_bounds__(320) void kD2(
    const float* __restrict__ dws, const float* __restrict__ uws,
    const float* __restrict__ Bws, const float* __restrict__ Cws,
    const float* __restrict__ A_log, const float* __restrict__ D_param,
    const float* __restrict__ rs_ws, const float* __restrict__ sc_ws,
    const float* __restrict__ tot_ws, float* __restrict__ out)
{
    __shared__ float yl[TBLK][21];
    const int tid = threadIdx.x;
    const int d   = tid >> 4;
    const int s   = tid & 15;
    const int b   = blockIdx.y;
    const int blk = blockIdx.x;
    const int bd  = b*DI + d;
    const size_t t0 = (size_t)blk*TBLK + s*K_;

    float d8[8], u8[8], du8[8];
    ld8(d8, dws + (size_t)bd*L_ + t0);
    ld8(u8, uws + (size_t)bd*L_ + t0);
    #pragma unroll
    for (int j = 0; j < 8; j++) du8[j] = d8[j]*u8[j];

    // inclusive local delta prefix + 16-lane exclusive prefix of lane sums
    float lp[8];
    { float run = 0.0f;
      #pragma unroll
      for (int j = 0; j < 8; j++) { run += d8[j]; lp[j] = run; } }
    float inc = lp[7];
    #pragma unroll
    for (int off = 1; off < 16; off <<= 1) {
        float t = __shfl_up(inc, off, 16);
        if (s >= off) inc += t;
    }
    float ex = __shfl_up(inc, 1, 16);
    if (s == 0) ex = 0.0f;
    const float base = sc_ws[(size_t)bd*NCB + blk] + ex;  // prefix before this lane
    const float Tot  = tot_ws[bd];

    float yacc[8];
    #pragma unroll
    for (int j = 0; j < 8; j++) yacc[j] = 0.0f;

    // prefetch n=0
    float B8[8], C8[8];
    ld8(B8, Bws + (size_t)(b*NS)*L_ + t0);
    ld8(C8, Cws + (size_t)(b*NS)*L_ + t0);

    #pragma unroll 1
    for (int n = 0; n < NS; n++) {
        float nB8[8], nC8[8];
        if (n + 1 < NS) {
            ld8(nB8, Bws + (size_t)(b*NS + n + 1)*L_ + t0);
            ld8(nC8, Cws + (size_t)(b*NS + n + 1)*L_ + t0);
        }
        const float A = -__expf(A_log[d*NS + n]);
        float a8[8], b8[8];
        #pragma unroll
        for (int j = 0; j < 8; j++) {
            a8[j] = __expf(A*d8[j]);
            b8[j] = du8[j]*B8[j];
        }
        float Ac = 1.0f, Bc = 0.0f;
        #pragma unroll
        for (int j = 0; j < 8; j++) { Bc = fmaf(a8[j], Bc, b8[j]); Ac *= a8[j]; }
        #pragma unroll
        for (int off = 1; off < 16; off <<= 1) {
            float aP = __shfl_up(Ac, off, 16);
            float bP = __shfl_up(Bc, off, 16);
            if (s >= off) { Bc = fmaf(Ac, bP, Bc); Ac *= aP; }
        }
        float pA = __shfl_up(Ac, 1, 16);
        float pB = __shfl_up(Bc, 1, 16);
        if (s == 0) { pA = 1.0f; pB = 0.0f; }
        float r = fmaf(pA, rs_ws[((size_t)bd*NS + n)*NCB + blk], pB);

        // damp chain: G[j] = exp(A*(Tot - pref_j)); G[j] = G[j+1]*a8[j+1]
        float G[8];
        G[7] = __expf(A*(Tot - (base + lp[7])));
        #pragma unroll
        for (int j = 6; j >= 0; j--) G[j] = G[j+1]*a8[j+1];
        #pragma unroll
        for (int j = 0; j < 8; j++) {
            r = fmaf(a8[j], r, b8[j]);
            float damp = G[j] * __builtin_amdgcn_rcpf(G[j] + 1e-12f);
            yacc[j] = fmaf(C8[j]*damp, r, yacc[j]);
        }
        if (n + 1 < NS) {
            #pragma unroll
            for (int j = 0; j < 8; j++) { B8[j] = nB8[j]; C8[j] = nC8[j]; }
        }
    }

    const float Dd = D_param[d];
    #pragma unroll
    for (int j = 0; j < 8; j++) yl[s*K_ + j][d] = fmaf(u8[j], Dd, yacc[j]);
    __syncthreads();

    // cooperative coalesced float4 store of the [128][20] tile
    float4* ob = (float4*)(out + ((size_t)b*L_ + (size_t)blk*TBLK)*DI);
    for (int i = tid; i < TBLK*DI/4; i += 320) {
        int t = i / 5, q = (i - t*5)*4;
        ob[i] = make_float4(yl[t][q], yl[t][q+1], yl[t][q+2], yl[t][q+3]);
    }
}

extern "C" void kernel_launch(void* const* d_in, const int* in_sizes, int n_in,
                              void* d_out, int out_size, void* d_ws, size_t ws_size,
                              hipStream_t stream) {
    const float* x      = (const float*)d_in[0];
    const float* w_in   = (const float*)d_in[1];
    const float* b_in   = (const float*)d_in[2];
    const float* conv_k = (const float*)d_in[3];
    const float* conv_b = (const float*)d_in[4];
    const float* w_x    = (const float*)d_in[5];
    const float* b_x    = (const float*)d_in[6];
    const float* w_dt   = (const float*)d_in[7];
    const float* b_dt   = (const float*)d_in[8];
    const float* A_log  = (const float*)d_in[9];
    const float* D_par  = (const float*)d_in[10];
    float* out = (float*)d_out;
    float* ws  = (float*)d_ws;

    float* dws    = ws + OFF_D;
    float* uws    = ws + OFF_U;
    float* Bws    = ws + OFF_B;
    float* Cws    = ws + OFF_C;
    float* ap_ws  = ws + OFF_AP;
    float* rs_ws  = ws + OFF_RS;
    float* sc_ws  = ws + OFF_SC;
    float* tot_ws = ws + OFF_TOT;

    k1<<<dim3(NCB, B_), 320, 0, stream>>>(x, w_in, b_in, conv_k, conv_b,
                                          w_x, b_x, w_dt, b_dt, A_log,
                                          dws, uws, Bws, Cws,
                                          ap_ws, rs_ws, sc_ws);
    kC2<<<B_*DI, 64, 0, stream>>>(ap_ws, rs_ws, sc_ws, tot_ws);
    kD2<<<dim3(NCB, B_), 320, 0, stream>>>(dws, uws, Bws, Cws, A_log, D_par,
                                           rs_ws, sc_ws, tot_ws, out);
}

// Round 6
// 158.352 us; speedup vs baseline: 1.1269x; 1.1269x over previous
//
#include <hip/hip_runtime.h>
#include <math.h>

#define B_   4
#define L_   32768
#define DI   20
#define NS   10
#define TBLK 128          // timesteps per chunk/block
#define NCB  256          // chunks per batch

// fp32 summary offsets in ws (floats)
#define OFF_AP  0u
#define OFF_RS  204800u
#define OFF_SC  409600u
#define OFF_TOT 430080u
#define OFF_H16 430160u   // fp16 region starts here (16B aligned)
// fp16 offsets (halves) within the h16 region
#define HD  0u            // delta [80][32768]
#define HU  2621440u      // u     [80][32768]
#define HB  5242880u      // B     [40][32768]
#define HC  6553600u      // C     [40][32768]

typedef _Float16 h16;
typedef _Float16 half8 __attribute__((ext_vector_type(8)));

// ---- DPP helpers: row_shr within 16-lane rows, OOB lanes -> identity ----
template<int CTRL>
__device__ __forceinline__ float dppf(float idv, float src) {
    union U { float f; int i; };
    U o, s, r; o.f = idv; s.f = src;
    r.i = __builtin_amdgcn_update_dpp(o.i, s.i, CTRL, 0xf, 0xf, false);
    return r.f;
}
#define ROW_SHR1 0x111
#define ROW_SHR2 0x112
#define ROW_SHR4 0x114
#define ROW_SHR8 0x118

// inclusive 16-lane scan of linear-recurrence op (A,B): x_out = A x + B
#define OPSCAN16(Ac, Bc) \
    { float aP = dppf<ROW_SHR1>(1.0f, Ac); float bP = dppf<ROW_SHR1>(0.0f, Bc); \
      Bc = fmaf(Ac, bP, Bc); Ac *= aP; \
      aP = dppf<ROW_SHR2>(1.0f, Ac); bP = dppf<ROW_SHR2>(0.0f, Bc); \
      Bc = fmaf(Ac, bP, Bc); Ac *= aP; \
      aP = dppf<ROW_SHR4>(1.0f, Ac); bP = dppf<ROW_SHR4>(0.0f, Bc); \
      Bc = fmaf(Ac, bP, Bc); Ac *= aP; \
      aP = dppf<ROW_SHR8>(1.0f, Ac); bP = dppf<ROW_SHR8>(0.0f, Bc); \
      Bc = fmaf(Ac, bP, Bc); Ac *= aP; }

// inclusive 16-lane sum scan
#define SUMSCAN16(v) \
    { v += dppf<ROW_SHR1>(0.0f, v); v += dppf<ROW_SHR2>(0.0f, v); \
      v += dppf<ROW_SHR4>(0.0f, v); v += dppf<ROW_SHR8>(0.0f, v); }

// ---- k1 LDS layout (halves). Pool = 9088 halves = 18176 B ----
#define WW   0      // w_in  [20][20] (first-half cols)   400
#define CK   400    // conv_k (w,i,o)                     1200
#define WX   1600   // w_x   [20][25]                     500
#define WDT  2100   // w_dt  [5][20]                      100
#define BIN  2200
#define CBo  2220
#define BX   2240
#define BDT  2265   // weights end 2285 (region 0..2288)
// transient (P0/P1): xs [130][22] @2288, h2 [130][22] @5148, end 8008
#define XS   2288
#define H2   5148
// staging (alias, written after P1b): all 8-half aligned
#define DS   2288   // delta [20][136]  -> 2720
#define DUS  5008   // delta*u [20][136]-> 2720
#define BS   7728   // B [10][136]      -> 1360, end 9088

// =============== k1: pointwise + chunk-local scan ===============
__global__ __launch_bounds__(320) void k1(
    const float* __restrict__ x, const float* __restrict__ w_in,
    const float* __restrict__ b_in, const float* __restrict__ conv_k,
    const float* __restrict__ conv_b, const float* __restrict__ w_x,
    const float* __restrict__ b_x, const float* __restrict__ w_dt,
    const float* __restrict__ b_dt, const float* __restrict__ A_log,
    h16* __restrict__ dh, h16* __restrict__ uh,
    h16* __restrict__ Bh, h16* __restrict__ Ch,
    float* __restrict__ ap_ws, float* __restrict__ rs_ws, float* __restrict__ sc_ws)
{
    __shared__ __align__(16) h16 pool[9088];

    const int tid = threadIdx.x;
    const int c   = blockIdx.x;
    const int b   = blockIdx.y;
    const int l0  = c * TBLK;

    // ---------- P0: weights + x rows (fp16) ----------
    for (int i = tid; i < 400;  i += 320) pool[WW  + i] = (h16)w_in[(i/20)*40 + (i%20)];
    for (int i = tid; i < 1200; i += 320) pool[CK  + i] = (h16)conv_k[i];
    for (int i = tid; i < 500;  i += 320) pool[WX  + i] = (h16)w_x[i];
    for (int i = tid; i < 100;  i += 320) pool[WDT + i] = (h16)w_dt[i];
    if (tid < 20) { pool[BIN+tid] = (h16)b_in[tid]; pool[CBo+tid] = (h16)conv_b[tid];
                    pool[BDT+tid] = (h16)b_dt[tid]; }
    if (tid < 25) pool[BX+tid] = (h16)b_x[tid];
    for (int idx = tid; idx < 130*20; idx += 320) {
        int p = idx / 20, i = idx - p*20;
        int l = l0 - 2 + p;
        pool[XS + p*22 + i] = (l >= 0) ? (h16)x[((size_t)b*L_ + l)*DI + i] : (h16)0.0f;
    }
    __syncthreads();

    // ---------- P1a: h2 = x @ w_in[:, :20] + b_in ----------
    for (int tau = tid; tau < 260; tau += 320) {
        int p = tau >> 1, hb = tau & 1, ob2 = hb*10;
        int l = l0 - 2 + p;
        float acc[10];
        if (l < 0) {
            #pragma unroll
            for (int o = 0; o < 10; o++) acc[o] = 0.0f;
        } else {
            #pragma unroll
            for (int o = 0; o < 10; o++) acc[o] = (float)pool[BIN + ob2 + o];
            #pragma unroll
            for (int i = 0; i < 20; i++) {
                float xv = (float)pool[XS + p*22 + i];
                #pragma unroll
                for (int o = 0; o < 10; o++)
                    acc[o] = fmaf(xv, (float)pool[WW + i*20 + ob2 + o], acc[o]);
            }
        }
        #pragma unroll
        for (int o = 0; o < 10; o++) pool[H2 + p*22 + ob2 + o] = (h16)acc[o];
    }
    __syncthreads();

    // ---------- P1b: conv3+silu, x-proj, dt-softmax (2 threads/timestep) ------
    float u10[10], dl[10], xp[25];
    const int tl = tid >> 1, hf = tid & 1, ob = hf*10;
    if (tid < 256) {
        #pragma unroll
        for (int o = 0; o < 10; o++) u10[o] = (float)pool[CBo + ob + o];
        #pragma unroll
        for (int w = 0; w < 3; w++) {
            #pragma unroll
            for (int i = 0; i < 20; i++) {
                float hv = (float)pool[H2 + (tl + w)*22 + i];
                const int ck = CK + (w*20 + i)*20 + ob;
                #pragma unroll
                for (int o = 0; o < 10; o++) u10[o] = fmaf(hv, (float)pool[ck + o], u10[o]);
            }
        }
        #pragma unroll
        for (int o = 0; o < 10; o++) u10[o] = u10[o] / (1.0f + __expf(-u10[o]));

        #pragma unroll
        for (int j = 0; j < 25; j++) xp[j] = hf ? 0.0f : (float)pool[BX + j];
        #pragma unroll
        for (int o = 0; o < 10; o++) {
            float uv = u10[o];
            #pragma unroll
            for (int j = 0; j < 25; j++)
                xp[j] = fmaf(uv, (float)pool[WX + (ob + o)*25 + j], xp[j]);
        }
        #pragma unroll
        for (int j = 0; j < 25; j++) xp[j] += __shfl_xor(xp[j], 1);

        #pragma unroll
        for (int d = 0; d < 10; d++) dl[d] = (float)pool[BDT + ob + d];
        #pragma unroll
        for (int r = 0; r < 5; r++) {
            float dv = xp[r];
            #pragma unroll
            for (int d = 0; d < 10; d++)
                dl[d] = fmaf(dv, (float)pool[WDT + r*20 + ob + d], dl[d]);
        }
        float m = dl[0];
        #pragma unroll
        for (int d = 1; d < 10; d++) m = fmaxf(m, dl[d]);
        m = fmaxf(m, __shfl_xor(m, 1));
        float sum = 0.0f;
        #pragma unroll
        for (int d = 0; d < 10; d++) { dl[d] = __expf(dl[d] - m); sum += dl[d]; }
        sum += __shfl_xor(sum, 1);
        float inv = 1.0f / sum;
        #pragma unroll
        for (int d = 0; d < 10; d++) dl[d] *= inv;
    }
    __syncthreads();   // xs/h2 dead -> staging may overwrite

    // ---------- write global fp16 + LDS staging ----------
    if (tid < 256) {
        const int l = l0 + tl;
        #pragma unroll
        for (int k = 0; k < 10; k++) {
            h16 dv = (h16)dl[k], uv = (h16)u10[k];
            size_t o = (size_t)(b*DI + ob + k)*L_ + l;
            dh[o] = dv;
            uh[o] = uv;
            pool[DS  + (ob + k)*136 + tl] = dv;
            pool[DUS + (ob + k)*136 + tl] = (h16)(dl[k]*u10[k]);
        }
        if (hf == 0) {
            #pragma unroll
            for (int n = 0; n < NS; n++) {
                h16 bv = (h16)xp[5 + n];
                Bh[(size_t)(b*NS + n)*L_ + l] = bv;
                pool[BS + n*136 + tl] = bv;
            }
        } else {
            #pragma unroll
            for (int n = 0; n < NS; n++)
                Ch[(size_t)(b*NS + n)*L_ + l] = (h16)xp[15 + n];
        }
    }
    __syncthreads();

    // ---------- P3: chunk-local scan (20 d x 16 lanes, 8 t/lane) ----------
    const int d  = tid >> 4;
    const int s  = tid & 15;
    const int bd = b*DI + d;

    float d8[8], du8[8];
    { half8 hv = *(const half8*)&pool[DS + d*136 + 8*s];
      #pragma unroll
      for (int j = 0; j < 8; j++) d8[j] = (float)hv[j]; }
    { half8 hv = *(const half8*)&pool[DUS + d*136 + 8*s];
      #pragma unroll
      for (int j = 0; j < 8; j++) du8[j] = (float)hv[j]; }

    float ssum = 0.0f;
    #pragma unroll
    for (int j = 0; j < 8; j++) ssum += d8[j];
    SUMSCAN16(ssum);
    if (s == 15) sc_ws[(size_t)bd*NCB + c] = ssum;   // inclusive at lane 15 = chunk total

    float A_dn[NS];
    #pragma unroll
    for (int n = 0; n < NS; n++) A_dn[n] = -__expf(A_log[d*NS + n]);

    #pragma unroll 1
    for (int n = 0; n < NS; n++) {
        half8 bv = *(const half8*)&pool[BS + n*136 + 8*s];
        float Ac = 1.0f, Bc = 0.0f;
        #pragma unroll
        for (int j = 0; j < 8; j++) {
            float a = __expf(A_dn[n]*d8[j]);
            Bc = fmaf(a, Bc, du8[j]*(float)bv[j]);
            Ac *= a;
        }
        OPSCAN16(Ac, Bc);
        if (s == 15) {
            size_t o = ((size_t)bd*NS + n)*NCB + c;
            ap_ws[o] = Ac;
            rs_ws[o] = Bc;
        }
    }
}

// =============== kC2: inter-chunk scan (one wave per (b,d)) ===============
// NOTE: sc_ws arrives holding per-chunk totals; leaves holding exclusive prefix.
__global__ __launch_bounds__(64) void kC2(
    const float* __restrict__ ap_ws, float* __restrict__ rs_ws,
    float* __restrict__ sc_ws, float* __restrict__ tot_ws)
{
    const int bd   = blockIdx.x;
    const int lane = threadIdx.x;
    const size_t sb = (size_t)bd*NCB + lane*4;

    float4 sv = *(const float4*)(sc_ws + sb);
    float l1 = sv.x, l2 = l1 + sv.y, l3 = l2 + sv.z, l4 = l3 + sv.w;
    float inc = l4;
    #pragma unroll
    for (int off = 1; off < 64; off <<= 1) {
        float t = __shfl_up(inc, off);
        if (lane >= off) inc += t;
    }
    float ex = __shfl_up(inc, 1);
    if (lane == 0) ex = 0.0f;
    *(float4*)(sc_ws + sb) = make_float4(ex, ex + l1, ex + l2, ex + l3);
    if (lane == 63) tot_ws[bd] = inc;

    #pragma unroll 1
    for (int n = 0; n < NS; n++) {
        const size_t base = ((size_t)bd*NS + n)*NCB + lane*4;
        float4 av = *(const float4*)(ap_ws + base);
        float4 rv = *(const float4*)(rs_ws + base);
        float Ac = av.x, Bc = rv.x;
        Bc = fmaf(av.y, Bc, rv.y); Ac *= av.y;
        Bc = fmaf(av.z, Bc, rv.z); Ac *= av.z;
        Bc = fmaf(av.w, Bc, rv.w); Ac *= av.w;
        #pragma unroll
        for (int off = 1; off < 64; off <<= 1) {
            float aP = __shfl_up(Ac, off);
            float bP = __shfl_up(Bc, off);
            if (lane >= off) { Bc = fmaf(Ac, bP, Bc); Ac *= aP; }
        }
        float pB = __shfl_up(Bc, 1);
        if (lane == 0) pB = 0.0f;
        float r  = pB;
        float o0 = r; r = fmaf(av.x, r, rv.x);
        float o1 = r; r = fmaf(av.y, r, rv.y);
        float o2 = r; r = fmaf(av.z, r, rv.z);
        float o3 = r;
        *(float4*)(rs_ws + base) = make_float4(o0, o1, o2, o3);
    }
}

// =============== kD: final scan + damp + y ===============
__global__ __launch_bounds__(320) void kD(
    const h16* __restrict__ dh, const h16* __restrict__ uh,
    const h16* __restrict__ Bh, const h16* __restrict__ Ch,
    const float* __restrict__ A_log, const float* __restrict__ D_param,
    const float* __restrict__ rs_ws, const float* __restrict__ sc_ws,
    const float* __restrict__ tot_ws, float* __restrict__ out)
{
    __shared__ float ylT[20*132];     // y in [d][t] layout
    const int tid = threadIdx.x;
    const int d   = tid >> 4;
    const int s   = tid & 15;
    const int c   = blockIdx.x;
    const int b   = blockIdx.y;
    const int bd  = b*DI + d;
    const size_t t0 = (size_t)c*TBLK + s*8;

    float d8[8], u8[8], du8[8];
    { half8 hv = *(const half8*)(dh + (size_t)bd*L_ + t0);
      #pragma unroll
      for (int j = 0; j < 8; j++) d8[j] = (float)hv[j]; }
    { half8 hv = *(const half8*)(uh + (size_t)bd*L_ + t0);
      #pragma unroll
      for (int j = 0; j < 8; j++) u8[j] = (float)hv[j]; }
    #pragma unroll
    for (int j = 0; j < 8; j++) du8[j] = d8[j]*u8[j];

    // local delta inclusive prefix + exclusive lane prefix (DPP)
    float lp[8];
    { float run = 0.0f;
      #pragma unroll
      for (int j = 0; j < 8; j++) { run += d8[j]; lp[j] = run; } }
    float inc = lp[7];
    SUMSCAN16(inc);
    float ex = dppf<ROW_SHR1>(0.0f, inc);
    const float basep = sc_ws[(size_t)bd*NCB + c] + ex;
    const float Tot   = tot_ws[bd];

    float A_dn[NS], rin[NS];
    #pragma unroll
    for (int n = 0; n < NS; n++) {
        A_dn[n] = -__expf(A_log[d*NS + n]);
        rin[n]  = rs_ws[((size_t)bd*NS + n)*NCB + c];
    }

    float yacc[8];
    #pragma unroll
    for (int j = 0; j < 8; j++) yacc[j] = 0.0f;

    #pragma unroll 1
    for (int n = 0; n < NS; n++) {
        half8 bv = *(const half8*)(Bh + (size_t)(b*NS + n)*L_ + t0);
        half8 cv = *(const half8*)(Ch + (size_t)(b*NS + n)*L_ + t0);
        float a8[8], b8[8];
        #pragma unroll
        for (int j = 0; j < 8; j++) {
            a8[j] = __expf(A_dn[n]*d8[j]);
            b8[j] = du8[j]*(float)bv[j];
        }
        float Ac = 1.0f, Bc = 0.0f;
        #pragma unroll
        for (int j = 0; j < 8; j++) { Bc = fmaf(a8[j], Bc, b8[j]); Ac *= a8[j]; }
        OPSCAN16(Ac, Bc);
        float pA = dppf<ROW_SHR1>(1.0f, Ac);
        float pB = dppf<ROW_SHR1>(0.0f, Bc);
        float r  = fmaf(pA, rin[n], pB);

        float G[8];
        G[7] = __expf(A_dn[n]*(Tot - (basep + lp[7])));
        #pragma unroll
        for (int j = 6; j >= 0; j--) G[j] = G[j+1]*a8[j+1];
        #pragma unroll
        for (int j = 0; j < 8; j++) {
            r = fmaf(a8[j], r, b8[j]);
            float damp = G[j] * __builtin_amdgcn_rcpf(G[j] + 1e-12f);
            yacc[j] = fmaf((float)cv[j]*damp, r, yacc[j]);
        }
    }

    const float Dd = D_param[d];
    float yv[8];
    #pragma unroll
    for (int j = 0; j < 8; j++) yv[j] = fmaf(u8[j], Dd, yacc[j]);
    *(float4*)&ylT[d*132 + 8*s]     = *(float4*)(yv);
    *(float4*)&ylT[d*132 + 8*s + 4] = *(float4*)(yv + 4);
    __syncthreads();

    float4* ob4 = (float4*)(out + ((size_t)b*L_ + (size_t)c*TBLK)*DI);
    for (int i = tid; i < TBLK*DI/4; i += 320) {
        int t = i / 5, q = (i - t*5)*4;
        ob4[i] = make_float4(ylT[q*132 + t], ylT[(q+1)*132 + t],
                             ylT[(q+2)*132 + t], ylT[(q+3)*132 + t]);
    }
}

extern "C" void kernel_launch(void* const* d_in, const int* in_sizes, int n_in,
                              void* d_out, int out_size, void* d_ws, size_t ws_size,
                              hipStream_t stream) {
    const float* x      = (const float*)d_in[0];
    const float* w_in   = (const float*)d_in[1];
    const float* b_in   = (const float*)d_in[2];
    const float* conv_k = (const float*)d_in[3];
    const float* conv_b = (const float*)d_in[4];
    const float* w_x    = (const float*)d_in[5];
    const float* b_x    = (const float*)d_in[6];
    const float* w_dt   = (const float*)d_in[7];
    const float* b_dt   = (const float*)d_in[8];
    const float* A_log  = (const float*)d_in[9];
    const float* D_par  = (const float*)d_in[10];
    float* out = (float*)d_out;
    float* ws  = (float*)d_ws;

    float* ap_ws  = ws + OFF_AP;
    float* rs_ws  = ws + OFF_RS;
    float* sc_ws  = ws + OFF_SC;
    float* tot_ws = ws + OFF_TOT;
    h16*   hbase  = (h16*)(ws + OFF_H16);
    h16* dh = hbase + HD;
    h16* uh = hbase + HU;
    h16* Bh = hbase + HB;
    h16* Ch = hbase + HC;

    k1<<<dim3(NCB, B_), 320, 0, stream>>>(x, w_in, b_in, conv_k, conv_b,
                                          w_x, b_x, w_dt, b_dt, A_log,
                                          dh, uh, Bh, Ch,
                                          ap_ws, rs_ws, sc_ws);
    kC2<<<B_*DI, 64, 0, stream>>>(ap_ws, rs_ws, sc_ws, tot_ws);
    kD<<<dim3(NCB, B_), 320, 0, stream>>>(dh, uh, Bh, Ch, A_log, D_par,
                                          rs_ws, sc_ws, tot_ws, out);
}

// Round 7
// 143.487 us; speedup vs baseline: 1.2436x; 1.1036x over previous
//
#include <hip/hip_runtime.h>
#include <math.h>

#define B_   4
#define L_   32768
#define DI   20
#define NS   10
#define TBLK 128          // timesteps per chunk/block
#define NCB  256          // chunks per batch

// fp32 summary offsets in ws (floats)
#define OFF_AP  0u
#define OFF_RS  204800u
#define OFF_SC  409600u
#define OFF_TOT 430080u
#define OFF_H16 430160u   // fp16 region starts here
// fp16 offsets (halves)
#define HD  0u            // delta [80][32768]
#define HU  2621440u      // u     [80][32768]
#define HB  5242880u      // B     [40][32768]
#define HC  6553600u      // C     [40][32768]

typedef _Float16 h16;
typedef _Float16 half8 __attribute__((ext_vector_type(8)));
typedef float f32x4 __attribute__((ext_vector_type(4)));

// ---- DPP helpers: row_shr within 16-lane rows, OOB lanes -> identity ----
template<int CTRL>
__device__ __forceinline__ float dppf(float idv, float src) {
    union U { float f; int i; };
    U o, s, r; o.f = idv; s.f = src;
    r.i = __builtin_amdgcn_update_dpp(o.i, s.i, CTRL, 0xf, 0xf, false);
    return r.f;
}
#define ROW_SHR1 0x111
#define ROW_SHR2 0x112
#define ROW_SHR4 0x114
#define ROW_SHR8 0x118

#define OPSCAN16(Ac, Bc) \
    { float aP = dppf<ROW_SHR1>(1.0f, Ac); float bP = dppf<ROW_SHR1>(0.0f, Bc); \
      Bc = fmaf(Ac, bP, Bc); Ac *= aP; \
      aP = dppf<ROW_SHR2>(1.0f, Ac); bP = dppf<ROW_SHR2>(0.0f, Bc); \
      Bc = fmaf(Ac, bP, Bc); Ac *= aP; \
      aP = dppf<ROW_SHR4>(1.0f, Ac); bP = dppf<ROW_SHR4>(0.0f, Bc); \
      Bc = fmaf(Ac, bP, Bc); Ac *= aP; \
      aP = dppf<ROW_SHR8>(1.0f, Ac); bP = dppf<ROW_SHR8>(0.0f, Bc); \
      Bc = fmaf(Ac, bP, Bc); Ac *= aP; }

#define SUMSCAN16(v) \
    { v += dppf<ROW_SHR1>(0.0f, v); v += dppf<ROW_SHR2>(0.0f, v); \
      v += dppf<ROW_SHR4>(0.0f, v); v += dppf<ROW_SHR8>(0.0f, v); }

// ---- k1 LDS layout (halves) ----
// region A (0..9216): Xwin [128][72]; later uL[128][40]@0, xp5[128][6]@5120, DUS[20][136]@5888
#define XW    0
#define UL    0
#define XP5   5120
#define DUS   5888
// region B (9216..11936): w_in(400)+ck(1200) staging -> MeffT[32][72] -> DS[20][136]
#define RB    9216
#define DS_   9216
// region C (11936..13296): WxT[32][40] -> BS[10][136]
#define RC    11936
// misc
#define WDT_  13296
#define BDT_  13396
#define BX_   13416
#define POOLH 13448

// =============== k1: MFMA front-end + chunk-local scan ===============
__global__ __launch_bounds__(320) void k1(
    const float* __restrict__ x, const float* __restrict__ w_in,
    const float* __restrict__ b_in, const float* __restrict__ conv_k,
    const float* __restrict__ conv_b, const float* __restrict__ w_x,
    const float* __restrict__ b_x, const float* __restrict__ w_dt,
    const float* __restrict__ b_dt, const float* __restrict__ A_log,
    h16* __restrict__ dh, h16* __restrict__ uh,
    h16* __restrict__ Bh, h16* __restrict__ Ch,
    float* __restrict__ ap_ws, float* __restrict__ rs_ws, float* __restrict__ sc_ws)
{
    __shared__ __align__(16) h16 P[POOLH];
    __shared__ float beff_s[20];

    const int tid = threadIdx.x;
    const int c   = blockIdx.x;
    const int b   = blockIdx.y;
    const int l0  = c * TBLK;

    // ---------- P0: stage weights + x window ----------
    for (int i = tid; i < 400;  i += 320) P[RB + i]       = (h16)w_in[(i/20)*40 + (i%20)];
    for (int i = tid; i < 1200; i += 320) P[RB + 400 + i] = (h16)conv_k[i];
    // WxT[j(row 0..31)][k=d(col 0..31)] : w_x[d][j] for j<25,d<20 else 0
    for (int i = tid; i < 1024; i += 320) {
        int j = i >> 5, k = i & 31;
        P[RC + j*40 + k] = (j < 25 && k < 20) ? (h16)w_x[k*25 + j] : (h16)0.0f;
    }
    for (int i = tid; i < 100; i += 320) P[WDT_ + i] = (h16)w_dt[i];
    if (tid < 20) P[BDT_ + tid] = (h16)b_dt[tid];
    if (tid < 25) P[BX_  + tid] = (h16)b_x[tid];
    // Xwin[t][col] : col = w*20+i -> x[l0+t-2+w][i], cols 60..63 zero
    for (int idx = tid; idx < 128*64; idx += 320) {
        int t = idx >> 6, col = idx & 63;
        float v = 0.0f;
        if (col < 60) {
            int w = col / 20, i = col - w*20;
            int l = l0 + t - 2 + w;
            if (l >= 0) v = x[((size_t)b*L_ + l)*DI + i];
        }
        P[XW + t*72 + col] = (h16)v;
    }
    __syncthreads();

    // ---------- P1: Meff = w_in @ conv_k (per tap), beff ----------
    float me[4]; int mei[4];
    #pragma unroll
    for (int r = 0; r < 4; r++) {
        int e = tid + r*320;
        float acc = 0.0f;
        if (e < 1200) {
            int cc = e / 20, o = e - cc*20;     // cc=(w,i) 0..59, o 0..19
            int w = cc / 20, i = cc - w*20;
            #pragma unroll
            for (int op = 0; op < 20; op++)
                acc = fmaf((float)P[RB + i*20 + op],
                           (float)P[RB + 400 + (w*20 + op)*20 + o], acc);
        }
        me[r] = acc; mei[r] = e;
    }
    float be = 0.0f;
    if (tid < 20) {
        be = conv_b[tid];
        #pragma unroll
        for (int w = 0; w < 3; w++)
            #pragma unroll
            for (int op = 0; op < 20; op++)
                be = fmaf(b_in[op], (float)P[RB + 400 + (w*20 + op)*20 + tid], be);
    }
    __syncthreads();
    // write MeffT[d=o(row)][k=cc(col)], zero rows 20..31 and cols 60..63
    #pragma unroll
    for (int r = 0; r < 4; r++) {
        int e = mei[r];
        if (e < 1200) {
            int cc = e / 20, o = e - cc*20;
            P[RB + o*72 + cc] = (h16)me[r];
        }
    }
    for (int i = tid; i < 848; i += 320) {
        int rr, kk;
        if (i < 768) { rr = 20 + (i >> 6); kk = i & 63; }
        else         { int z = i - 768; rr = z >> 2; kk = 60 + (z & 3); }
        P[RB + rr*72 + kk] = (h16)0.0f;
    }
    if (tid < 20) beff_s[tid] = be;
    __syncthreads();

    // ---------- P2: u_pre = Xwin @ Meff (MFMA), +beff, silu ----------
    const int wv  = tid >> 6;
    const int ln  = tid & 63;
    const int m16 = ln & 15;
    const int q   = ln >> 4;
    float uval[4][4];
    if (wv < 4) {
        #pragma unroll
        for (int jj = 0; jj < 4; jj++) {
            int job = wv*4 + jj, mt = job >> 1, nt = job & 1;
            f32x4 acc = {0.0f, 0.0f, 0.0f, 0.0f};
            half8 a0 = *(const half8*)&P[XW + (mt*16 + m16)*72 + q*8];
            half8 b0 = *(const half8*)&P[RB + (nt*16 + m16)*72 + q*8];
            acc = __builtin_amdgcn_mfma_f32_16x16x32_f16(a0, b0, acc, 0, 0, 0);
            half8 a1 = *(const half8*)&P[XW + (mt*16 + m16)*72 + 32 + q*8];
            half8 b1 = *(const half8*)&P[RB + (nt*16 + m16)*72 + 32 + q*8];
            acc = __builtin_amdgcn_mfma_f32_16x16x32_f16(a1, b1, acc, 0, 0, 0);
            int d = nt*16 + m16;
            float bf = (d < 20) ? beff_s[d] : 0.0f;
            #pragma unroll
            for (int r = 0; r < 4; r++) {
                float a = acc[r] + bf;
                uval[jj][r] = a / (1.0f + __expf(-a));
            }
        }
    }
    __syncthreads();   // Xwin dead
    if (wv < 4) {
        #pragma unroll
        for (int jj = 0; jj < 4; jj++) {
            int job = wv*4 + jj, mt = job >> 1, nt = job & 1;
            int d = nt*16 + m16;
            if (d < 20) {
                #pragma unroll
                for (int r = 0; r < 4; r++)
                    P[UL + (mt*16 + q*4 + r)*40 + d] = (h16)uval[jj][r];
            }
        }
    }
    for (int i = tid; i < 128*12; i += 320) {       // zero uL cols 20..31
        int t = i / 12, z = i - t*12;
        P[UL + t*40 + 20 + z] = (h16)0.0f;
    }
    __syncthreads();

    // ---------- P3: xp = u @ w_x (MFMA), +b_x; stash cols 0..4 ----------
    float xv[4][4];
    if (wv < 4) {
        #pragma unroll
        for (int jj = 0; jj < 4; jj++) {
            int job = wv*4 + jj, mt = job >> 1, nt = job & 1;
            f32x4 acc = {0.0f, 0.0f, 0.0f, 0.0f};
            half8 a0 = *(const half8*)&P[UL + (mt*16 + m16)*40 + q*8];
            half8 b0 = *(const half8*)&P[RC + (nt*16 + m16)*40 + q*8];
            acc = __builtin_amdgcn_mfma_f32_16x16x32_f16(a0, b0, acc, 0, 0, 0);
            int j = nt*16 + m16;
            float bx = (j < 25) ? (float)P[BX_ + j] : 0.0f;
            #pragma unroll
            for (int r = 0; r < 4; r++) {
                xv[jj][r] = acc[r] + bx;
                if (j < 5) P[XP5 + (mt*16 + q*4 + r)*6 + j] = (h16)xv[jj][r];
            }
        }
    }
    __syncthreads();   // WxT dead; xp5 visible

    // ---------- P4: stage B (LDS+global), C (global); dt-softmax; stage d/du ----
    if (wv < 4) {
        #pragma unroll
        for (int jj = 0; jj < 4; jj++) {
            int job = wv*4 + jj, mt = job >> 1, nt = job & 1;
            int j = nt*16 + m16;
            #pragma unroll
            for (int r = 0; r < 4; r++) {
                int t = mt*16 + q*4 + r;
                h16 hv = (h16)xv[jj][r];
                if (j >= 5 && j < 15) {
                    P[RC + (j - 5)*136 + t] = hv;
                    Bh[(size_t)(b*NS + (j - 5))*L_ + l0 + t] = hv;
                } else if (j >= 15 && j < 25) {
                    Ch[(size_t)(b*NS + (j - 15))*L_ + l0 + t] = hv;
                }
            }
        }
    }
    if (tid < 128) {
        const int t = tid;
        float xq[5];
        #pragma unroll
        for (int r = 0; r < 5; r++) xq[r] = (float)P[XP5 + t*6 + r];
        float dtp[20];
        #pragma unroll
        for (int d2 = 0; d2 < 20; d2++) dtp[d2] = (float)P[BDT_ + d2];
        #pragma unroll
        for (int r = 0; r < 5; r++) {
            float dv = xq[r];
            #pragma unroll
            for (int d2 = 0; d2 < 20; d2++)
                dtp[d2] = fmaf(dv, (float)P[WDT_ + r*20 + d2], dtp[d2]);
        }
        float mx = dtp[0];
        #pragma unroll
        for (int d2 = 1; d2 < 20; d2++) mx = fmaxf(mx, dtp[d2]);
        float sm = 0.0f;
        #pragma unroll
        for (int d2 = 0; d2 < 20; d2++) { dtp[d2] = __expf(dtp[d2] - mx); sm += dtp[d2]; }
        float inv = 1.0f / sm;
        #pragma unroll
        for (int d2 = 0; d2 < 20; d2++) {
            h16 dlh = (h16)(dtp[d2] * inv);
            h16 uvh = P[UL + t*40 + d2];
            P[DS_ + d2*136 + t] = dlh;
            P[DUS + d2*136 + t] = (h16)((float)dlh * (float)uvh);
            size_t o = (size_t)(b*DI + d2)*L_ + l0 + t;
            dh[o] = dlh;
            uh[o] = uvh;
        }
    }
    __syncthreads();

    // ---------- P5: chunk-local scan (20 d x 16 lanes, 8 t/lane) ----------
    const int d  = tid >> 4;
    const int s  = tid & 15;
    const int bd = b*DI + d;

    float d8[8], du8[8];
    { half8 hv = *(const half8*)&P[DS_ + d*136 + 8*s];
      #pragma unroll
      for (int j = 0; j < 8; j++) d8[j] = (float)hv[j]; }
    { half8 hv = *(const half8*)&P[DUS + d*136 + 8*s];
      #pragma unroll
      for (int j = 0; j < 8; j++) du8[j] = (float)hv[j]; }

    float ssum = 0.0f;
    #pragma unroll
    for (int j = 0; j < 8; j++) ssum += d8[j];
    SUMSCAN16(ssum);
    if (s == 15) sc_ws[(size_t)bd*NCB + c] = ssum;

    float A_dn[NS];
    #pragma unroll
    for (int n = 0; n < NS; n++) A_dn[n] = -__expf(A_log[d*NS + n]);

    #pragma unroll 1
    for (int n = 0; n < NS; n++) {
        half8 bv = *(const half8*)&P[RC + n*136 + 8*s];
        float Ac = 1.0f, Bc = 0.0f;
        #pragma unroll
        for (int j = 0; j < 8; j++) {
            float a = __expf(A_dn[n]*d8[j]);
            Bc = fmaf(a, Bc, du8[j]*(float)bv[j]);
            Ac *= a;
        }
        OPSCAN16(Ac, Bc);
        if (s == 15) {
            size_t o = ((size_t)bd*NS + n)*NCB + c;
            ap_ws[o] = Ac;
            rs_ws[o] = Bc;
        }
    }
}

// =============== kC2: inter-chunk scan (one wave per (b,d)) ===============
__global__ __launch_bounds__(64) void kC2(
    const float* __restrict__ ap_ws, float* __restrict__ rs_ws,
    float* __restrict__ sc_ws, float* __restrict__ tot_ws)
{
    const int bd   = blockIdx.x;
    const int lane = threadIdx.x;
    const size_t sb = (size_t)bd*NCB + lane*4;

    float4 sv = *(const float4*)(sc_ws + sb);
    float l1 = sv.x, l2 = l1 + sv.y, l3 = l2 + sv.z, l4 = l3 + sv.w;
    float inc = l4;
    #pragma unroll
    for (int off = 1; off < 64; off <<= 1) {
        float t = __shfl_up(inc, off);
        if (lane >= off) inc += t;
    }
    float ex = __shfl_up(inc, 1);
    if (lane == 0) ex = 0.0f;
    *(float4*)(sc_ws + sb) = make_float4(ex, ex + l1, ex + l2, ex + l3);
    if (lane == 63) tot_ws[bd] = inc;

    #pragma unroll 1
    for (int n = 0; n < NS; n++) {
        const size_t base = ((size_t)bd*NS + n)*NCB + lane*4;
        float4 av = *(const float4*)(ap_ws + base);
        float4 rv = *(const float4*)(rs_ws + base);
        float Ac = av.x, Bc = rv.x;
        Bc = fmaf(av.y, Bc, rv.y); Ac *= av.y;
        Bc = fmaf(av.z, Bc, rv.z); Ac *= av.z;
        Bc = fmaf(av.w, Bc, rv.w); Ac *= av.w;
        #pragma unroll
        for (int off = 1; off < 64; off <<= 1) {
            float aP = __shfl_up(Ac, off);
            float bP = __shfl_up(Bc, off);
            if (lane >= off) { Bc = fmaf(Ac, bP, Bc); Ac *= aP; }
        }
        float pB = __shfl_up(Bc, 1);
        if (lane == 0) pB = 0.0f;
        float r  = pB;
        float o0 = r; r = fmaf(av.x, r, rv.x);
        float o1 = r; r = fmaf(av.y, r, rv.y);
        float o2 = r; r = fmaf(av.z, r, rv.z);
        float o3 = r;
        *(float4*)(rs_ws + base) = make_float4(o0, o1, o2, o3);
    }
}

// =============== kD: final scan + damp + y (with B/C prefetch) ===============
__global__ __launch_bounds__(320) void kD(
    const h16* __restrict__ dh, const h16* __restrict__ uh,
    const h16* __restrict__ Bh, const h16* __restrict__ Ch,
    const float* __restrict__ A_log, const float* __restrict__ D_param,
    const float* __restrict__ rs_ws, const float* __restrict__ sc_ws,
    const float* __restrict__ tot_ws, float* __restrict__ out)
{
    __shared__ float ylT[20*132];
    const int tid = threadIdx.x;
    const int d   = tid >> 4;
    const int s   = tid & 15;
    const int c   = blockIdx.x;
    const int b   = blockIdx.y;
    const int bd  = b*DI + d;
    const size_t t0 = (size_t)c*TBLK + s*8;

    float d8[8], u8[8], du8[8];
    { half8 hv = *(const half8*)(dh + (size_t)bd*L_ + t0);
      #pragma unroll
      for (int j = 0; j < 8; j++) d8[j] = (float)hv[j]; }
    { half8 hv = *(const half8*)(uh + (size_t)bd*L_ + t0);
      #pragma unroll
      for (int j = 0; j < 8; j++) u8[j] = (float)hv[j]; }
    #pragma unroll
    for (int j = 0; j < 8; j++) du8[j] = d8[j]*u8[j];

    float lp[8];
    { float run = 0.0f;
      #pragma unroll
      for (int j = 0; j < 8; j++) { run += d8[j]; lp[j] = run; } }
    float inc = lp[7];
    SUMSCAN16(inc);
    float ex = dppf<ROW_SHR1>(0.0f, inc);
    const float basep = sc_ws[(size_t)bd*NCB + c] + ex;
    const float Tot   = tot_ws[bd];

    float A_dn[NS], rin[NS];
    #pragma unroll
    for (int n = 0; n < NS; n++) {
        A_dn[n] = -__expf(A_log[d*NS + n]);
        rin[n]  = rs_ws[((size_t)bd*NS + n)*NCB + c];
    }

    float yacc[8];
    #pragma unroll
    for (int j = 0; j < 8; j++) yacc[j] = 0.0f;

    half8 bv = *(const half8*)(Bh + (size_t)(b*NS)*L_ + t0);
    half8 cv = *(const half8*)(Ch + (size_t)(b*NS)*L_ + t0);

    #pragma unroll 1
    for (int n = 0; n < NS; n++) {
        half8 bnx, cnx;
        if (n + 1 < NS) {
            bnx = *(const half8*)(Bh + (size_t)(b*NS + n + 1)*L_ + t0);
            cnx = *(const half8*)(Ch + (size_t)(b*NS + n + 1)*L_ + t0);
        }
        float a8[8], b8[8];
        #pragma unroll
        for (int j = 0; j < 8; j++) {
            a8[j] = __expf(A_dn[n]*d8[j]);
            b8[j] = du8[j]*(float)bv[j];
        }
        float Ac = 1.0f, Bc = 0.0f;
        #pragma unroll
        for (int j = 0; j < 8; j++) { Bc = fmaf(a8[j], Bc, b8[j]); Ac *= a8[j]; }
        OPSCAN16(Ac, Bc);
        float pA = dppf<ROW_SHR1>(1.0f, Ac);
        float pB = dppf<ROW_SHR1>(0.0f, Bc);
        float r  = fmaf(pA, rin[n], pB);

        float G[8];
        G[7] = __expf(A_dn[n]*(Tot - (basep + lp[7])));
        #pragma unroll
        for (int j = 6; j >= 0; j--) G[j] = G[j+1]*a8[j+1];
        #pragma unroll
        for (int j = 0; j < 8; j++) {
            r = fmaf(a8[j], r, b8[j]);
            float damp = G[j] * __builtin_amdgcn_rcpf(G[j] + 1e-12f);
            yacc[j] = fmaf((float)cv[j]*damp, r, yacc[j]);
        }
        if (n + 1 < NS) { bv = bnx; cv = cnx; }
    }

    const float Dd = D_param[d];
    float yv[8];
    #pragma unroll
    for (int j = 0; j < 8; j++) yv[j] = fmaf(u8[j], Dd, yacc[j]);
    *(float4*)&ylT[d*132 + 8*s]     = *(float4*)(yv);
    *(float4*)&ylT[d*132 + 8*s + 4] = *(float4*)(yv + 4);
    __syncthreads();

    float4* ob4 = (float4*)(out + ((size_t)b*L_ + (size_t)c*TBLK)*DI);
    for (int i = tid; i < TBLK*DI/4; i += 320) {
        int t = i / 5, qq = (i - t*5)*4;
        ob4[i] = make_float4(ylT[qq*132 + t], ylT[(qq+1)*132 + t],
                             ylT[(qq+2)*132 + t], ylT[(qq+3)*132 + t]);
    }
}

extern "C" void kernel_launch(void* const* d_in, const int* in_sizes, int n_in,
                              void* d_out, int out_size, void* d_ws, size_t ws_size,
                              hipStream_t stream) {
    const float* x      = (const float*)d_in[0];
    const float* w_in   = (const float*)d_in[1];
    const float* b_in   = (const float*)d_in[2];
    const float* conv_k = (const float*)d_in[3];
    const float* conv_b = (const float*)d_in[4];
    const float* w_x    = (const float*)d_in[5];
    const float* b_x    = (const float*)d_in[6];
    const float* w_dt   = (const float*)d_in[7];
    const float* b_dt   = (const float*)d_in[8];
    const float* A_log  = (const float*)d_in[9];
    const float* D_par  = (const float*)d_in[10];
    float* out = (float*)d_out;
    float* ws  = (float*)d_ws;

    float* ap_ws  = ws + OFF_AP;
    float* rs_ws  = ws + OFF_RS;
    float* sc_ws  = ws + OFF_SC;
    float* tot_ws = ws + OFF_TOT;
    h16*   hbase  = (h16*)(ws + OFF_H16);
    h16* dh = hbase + HD;
    h16* uh = hbase + HU;
    h16* Bh = hbase + HB;
    h16* Ch = hbase + HC;

    k1<<<dim3(NCB, B_), 320, 0, stream>>>(x, w_in, b_in, conv_k, conv_b,
                                          w_x, b_x, w_dt, b_dt, A_log,
                                          dh, uh, Bh, Ch,
                                          ap_ws, rs_ws, sc_ws);
    kC2<<<B_*DI, 64, 0, stream>>>(ap_ws, rs_ws, sc_ws, tot_ws);
    kD<<<dim3(NCB, B_), 320, 0, stream>>>(dh, uh, Bh, Ch, A_log, D_par,
                                          rs_ws, sc_ws, tot_ws, out);
}